// Round 1
// baseline (518.931 us; speedup 1.0000x reference)
//
#include <hip/hip_runtime.h>
#include <hip/hip_bf16.h>

#define BATCH   2048
#define DIM     512
#define DB_N    50000
#define TOPK    5
#define MSPLIT  16
#define CHUNK   3125        // DB_N / MSPLIT
#define BM      128         // batch rows per block (8 waves x 16)
#define BN      64          // db rows per tile
#define NTILES  49          // ceil(CHUNK / BN)
#define LDSPAD  72          // 64 + 8 bf16 pad -> 144B row stride, 2-way bank conflicts only

typedef float  f32x4  __attribute__((ext_vector_type(4)));
typedef short  bf16x8 __attribute__((ext_vector_type(8)));

__device__ __forceinline__ short f2bf(float f) {
    union { float f; unsigned u; } v; v.f = f;
    unsigned r = v.u + 0x7FFFu + ((v.u >> 16) & 1u);   // RNE
    return (short)(r >> 16);
}

__device__ __forceinline__ bf16x8 pack8(float4 a, float4 b) {
    bf16x8 r;
    r[0] = f2bf(a.x); r[1] = f2bf(a.y); r[2] = f2bf(a.z); r[3] = f2bf(a.w);
    r[4] = f2bf(b.x); r[5] = f2bf(b.y); r[6] = f2bf(b.z); r[7] = f2bf(b.w);
    return r;
}

// ---------------- kernel 1: inverse L2 norms of db rows ----------------
__global__ void inv_norm_kernel(const float* __restrict__ db, float* __restrict__ inv_db) {
    const int g    = blockIdx.x * (blockDim.x >> 6) + (threadIdx.x >> 6);
    const int lane = threadIdx.x & 63;
    if (g >= DB_N) return;
    const float* row = db + (size_t)g * DIM;
    const float4 a = *(const float4*)(row + lane * 8);
    const float4 b = *(const float4*)(row + lane * 8 + 4);
    float s = a.x*a.x + a.y*a.y + a.z*a.z + a.w*a.w
            + b.x*b.x + b.y*b.y + b.z*b.z + b.w*b.w;
    #pragma unroll
    for (int off = 32; off >= 1; off >>= 1) s += __shfl_xor(s, off);
    if (lane == 0) inv_db[g] = 1.0f / fmaxf(sqrtf(s), 1e-12f);
}

// ---------------- kernel 2: fused sim GEMM + running top-5 ----------------
__global__ __launch_bounds__(512, 1) void sim_topk_kernel(
    const float* __restrict__ h, const float* __restrict__ db,
    const float* __restrict__ inv_db,
    float* __restrict__ pv, int* __restrict__ pi) {

    __shared__ __align__(16) short tile[2][BN][LDSPAD];

    const int tid  = threadIdx.x;
    const int lane = tid & 63;
    const int wid  = tid >> 6;
    const int l15  = lane & 15;
    const int lhi  = lane >> 4;
    const int rb   = blockIdx.x >> 4;     // 0..15 row-block
    const int mc   = blockIdx.x & 15;     // 0..15 m-chunk
    const int m_base = mc * CHUNK;
    const int row_g  = rb * BM + wid * 16 + l15;

    // ---- load A (raw h rows) into registers as bf16, compute row norm on the fly
    const float* hrow = h + (size_t)row_g * DIM;
    float ss = 0.f;
    bf16x8 ha[16];
    #pragma unroll
    for (int t = 0; t < 16; ++t) {
        const float4 x = *(const float4*)(hrow + t * 32 + lhi * 8);
        const float4 y = *(const float4*)(hrow + t * 32 + lhi * 8 + 4);
        ss += x.x*x.x + x.y*x.y + x.z*x.z + x.w*x.w;
        ss += y.x*y.x + y.y*y.y + y.z*y.z + y.w*y.w;
        ha[t] = pack8(x, y);
    }
    ss += __shfl_xor(ss, 16);
    ss += __shfl_xor(ss, 32);
    const float inv_h = 1.0f / fmaxf(sqrtf(ss), 1e-12f);
    // inv_h for the C-layout rows this lane accumulates (row = lhi*4 + i)
    float ivc[4];
    #pragma unroll
    for (int i = 0; i < 4; ++i) ivc[i] = __shfl(inv_h, lhi * 4 + i, 64);

    // running top-5 (replicated across the 16 lanes of each group)
    float tv[4][TOPK]; int tix[4][TOPK];
    #pragma unroll
    for (int i = 0; i < 4; ++i)
        #pragma unroll
        for (int j = 0; j < TOPK; ++j) { tv[i][j] = -3.0e38f; tix[i][j] = 0; }

    const int srow = tid >> 3;         // staging: db row 0..63
    const int skc  = (tid & 7) * 8;    // staging: k offset (floats)

    for (int tt = 0; tt < NTILES; ++tt) {
        const int m0    = m_base + tt * BN;
        const int mrows = (m_base + CHUNK - m0 < BN) ? (m_base + CHUNK - m0) : BN;

        f32x4 acc[4];
        #pragma unroll
        for (int f = 0; f < 4; ++f) acc[f] = (f32x4){0.f, 0.f, 0.f, 0.f};

        // stage kb = 0
        {
            float4 x = {0,0,0,0}, y = {0,0,0,0};
            if (srow < mrows) {
                const float* p = db + (size_t)(m0 + srow) * DIM + skc;
                x = *(const float4*)p; y = *(const float4*)(p + 4);
            }
            *(bf16x8*)(&tile[0][srow][skc]) = pack8(x, y);
        }
        __syncthreads();

        #pragma unroll
        for (int kb = 0; kb < 8; ++kb) {
            // prefetch next k-chunk into registers (HBM latency hides under MFMA)
            float4 px = {0,0,0,0}, py = {0,0,0,0};
            if (kb < 7) {
                if (srow < mrows) {
                    const float* p = db + (size_t)(m0 + srow) * DIM + (kb + 1) * 64 + skc;
                    px = *(const float4*)p; py = *(const float4*)(p + 4);
                }
            }
            // compute on tile[kb&1]
            const short* tb = &tile[kb & 1][0][0];
            #pragma unroll
            for (int ks = 0; ks < 2; ++ks) {
                const bf16x8 a = ha[kb * 2 + ks];
                #pragma unroll
                for (int f = 0; f < 4; ++f) {
                    const bf16x8 bfr = *(const bf16x8*)(tb + (f * 16 + l15) * LDSPAD + ks * 32 + lhi * 8);
                    acc[f] = __builtin_amdgcn_mfma_f32_16x16x32_bf16(a, bfr, acc[f], 0, 0, 0);
                }
            }
            if (kb < 7) {
                *(bf16x8*)(&tile[(kb + 1) & 1][srow][skc]) = pack8(px, py);
                __syncthreads();
            }
        }

        // ---- scale to true cosine sims; mask invalid columns
        #pragma unroll
        for (int f = 0; f < 4; ++f) {
            const int  c     = f * 16 + l15;
            const bool valid = c < mrows;
            const float idb  = valid ? inv_db[m0 + c] : 0.f;
            #pragma unroll
            for (int i = 0; i < 4; ++i)
                acc[f][i] = valid ? acc[f][i] * ivc[i] * idb : -3.0e38f;
        }

        // ---- top-5 merge: iterative argmax-extract (4 rows/reg x 4 groups in parallel)
        #pragma unroll 1
        for (int it = 0; it < TOPK; ++it) {
            float wv[4]; int wc[4];
            #pragma unroll
            for (int i = 0; i < 4; ++i) {
                float v = acc[0][i]; int c = l15;
                #pragma unroll
                for (int f = 1; f < 4; ++f) {
                    const float v2 = acc[f][i]; const int c2 = f * 16 + l15;
                    if (v2 > v) { v = v2; c = c2; }
                }
                #pragma unroll
                for (int s = 1; s < 16; s <<= 1) {
                    const float ov = __shfl_xor(v, s);
                    const int   oc = __shfl_xor(c, s);
                    if (ov > v || (ov == v && oc < c)) { v = ov; c = oc; }
                }
                wv[i] = v; wc[i] = c;
            }
            int nb = 0;
            #pragma unroll
            for (int i = 0; i < 4; ++i) nb |= (wv[i] > tv[i][TOPK - 1]) ? 1 : 0;
            if (!__any(nb)) break;
            #pragma unroll
            for (int i = 0; i < 4; ++i) {
                const float w  = wv[i];
                const int   gi = m0 + wc[i];
                // branchless sorted insert (descending); no-op automatically if w <= tv[i][4]
                #pragma unroll
                for (int j = TOPK - 1; j >= 1; --j) {
                    const bool gt  = w > tv[i][j];
                    const bool gtp = w > tv[i][j - 1];
                    tv[i][j]  = gt ? (gtp ? tv[i][j - 1]  : w)  : tv[i][j];
                    tix[i][j] = gt ? (gtp ? tix[i][j - 1] : gi) : tix[i][j];
                }
                if (w > tv[i][0]) { tv[i][0] = w; tix[i][0] = gi; }
                // mask the winner out of acc
                #pragma unroll
                for (int f = 0; f < 4; ++f)
                    if (f * 16 + l15 == wc[i]) acc[f][i] = -3.0e38f;
            }
        }
    }

    // ---- write per-(row, chunk) partial top-5
    if (l15 == 0) {
        #pragma unroll
        for (int i = 0; i < 4; ++i) {
            const int    row  = rb * BM + wid * 16 + lhi * 4 + i;
            const size_t base = ((size_t)row * MSPLIT + mc) * TOPK;
            #pragma unroll
            for (int j = 0; j < TOPK; ++j) { pv[base + j] = tv[i][j]; pi[base + j] = tix[i][j]; }
        }
    }
}

// ---------------- kernel 3: merge chunks, softmax, gather, blend ----------------
__global__ void finalize_kernel(const float* __restrict__ h, const float* __restrict__ db,
                                const float* __restrict__ alpha_p,
                                const float* __restrict__ pv, const int* __restrict__ pi,
                                float* __restrict__ out) {
    const int b = blockIdx.x;
    __shared__ float mu_s[TOPK];
    __shared__ int   id_s[TOPK];
    if (threadIdx.x == 0) {
        float bv[TOPK]; int bi[TOPK];
        #pragma unroll
        for (int j = 0; j < TOPK; ++j) { bv[j] = -3.0e38f; bi[j] = 0; }
        const float* vp = pv + (size_t)b * MSPLIT * TOPK;
        const int*   ip = pi + (size_t)b * MSPLIT * TOPK;
        for (int c = 0; c < MSPLIT * TOPK; ++c) {
            const float w  = vp[c];
            const int   gi = ip[c];
            #pragma unroll
            for (int j = TOPK - 1; j >= 1; --j) {
                const bool gt  = w > bv[j];
                const bool gtp = w > bv[j - 1];
                bv[j] = gt ? (gtp ? bv[j - 1] : w)  : bv[j];
                bi[j] = gt ? (gtp ? bi[j - 1] : gi) : bi[j];
            }
            if (w > bv[0]) { bv[0] = w; bi[0] = gi; }
        }
        float s = 0.f, wts[TOPK];
        #pragma unroll
        for (int j = 0; j < TOPK; ++j) { wts[j] = expf(bv[j] - bv[0]); s += wts[j]; }
        #pragma unroll
        for (int j = 0; j < TOPK; ++j) { mu_s[j] = wts[j] / s; id_s[j] = bi[j]; }
    }
    __syncthreads();
    const float a = 1.0f / (1.0f + expf(-alpha_p[0]));
    for (int d = threadIdx.x; d < DIM; d += 256) {
        float r = 0.f;
        #pragma unroll
        for (int j = 0; j < TOPK; ++j) r += mu_s[j] * db[(size_t)id_s[j] * DIM + d];
        out[(size_t)b * DIM + d] = a * h[(size_t)b * DIM + d] + (1.f - a) * r;
    }
}

extern "C" void kernel_launch(void* const* d_in, const int* in_sizes, int n_in,
                              void* d_out, int out_size, void* d_ws, size_t ws_size,
                              hipStream_t stream) {
    const float* h     = (const float*)d_in[0];
    const float* db    = (const float*)d_in[1];
    const float* alpha = (const float*)d_in[2];
    float* out = (float*)d_out;

    // workspace layout: inv_db (50000 f32, padded) | pv (2048*16*5 f32) | pi (ints)
    float* inv_db = (float*)d_ws;
    float* pv     = (float*)((char*)d_ws + 200704);
    int*   pi     = (int*)  ((char*)d_ws + 200704 + 655360);

    inv_norm_kernel<<<(DB_N + 3) / 4, 256, 0, stream>>>(db, inv_db);
    sim_topk_kernel<<<16 * MSPLIT, 512, 0, stream>>>(h, db, inv_db, pv, pi);
    finalize_kernel<<<BATCH, 256, 0, stream>>>(h, db, alpha, pv, pi, out);
}

// Round 2
// 447.302 us; speedup vs baseline: 1.1601x; 1.1601x over previous
//
#include <hip/hip_runtime.h>
#include <hip/hip_bf16.h>

#define BATCH   2048
#define DIM     512
#define DB_N    50000
#define TOPK    5

// ---- fast path geometry ----
#define MSPLIT  32
#define CHUNK   1600        // multiple of 64; 32*1600 = 51200 padded rows
#define NTILES  25          // CHUNK / 64
#define PADN    51200
#define BM      128         // 8 waves x 16 rows
#define BN      64

// ---- fallback (round-1) geometry ----
#define FMSPLIT 16
#define FCHUNK  3125
#define FNTILES 49
#define LDSPAD  72

typedef float  f32x4  __attribute__((ext_vector_type(4)));
typedef short  bf16x8 __attribute__((ext_vector_type(8)));

__device__ __forceinline__ short f2bf(float f) {
    union { float f; unsigned u; } v; v.f = f;
    unsigned r = v.u + 0x7FFFu + ((v.u >> 16) & 1u);   // RNE
    return (short)(r >> 16);
}

__device__ __forceinline__ bf16x8 pack8(float4 a, float4 b) {
    bf16x8 r;
    r[0] = f2bf(a.x); r[1] = f2bf(a.y); r[2] = f2bf(a.z); r[3] = f2bf(a.w);
    r[4] = f2bf(b.x); r[5] = f2bf(b.y); r[6] = f2bf(b.z); r[7] = f2bf(b.w);
    return r;
}

__device__ __forceinline__ void async16(const void* g, void* l) {
    __builtin_amdgcn_global_load_lds(
        (const __attribute__((address_space(1))) unsigned int*)g,
        (__attribute__((address_space(3))) unsigned int*)l, 16, 0, 0);
}

// ============ kernel 0 (fast): normalize db -> bf16, k-chunked, pre-swizzled ============
// layout: unit(kb, r, w) at dbz[((kb*PADN + r)*8 + w)*8] holds data elems
//         db_norm[r][kb*64 + (w ^ (r&7))*8 .. +8]  (so linear DMA lands XOR-swizzled)
__global__ void convert_db_kernel(const float* __restrict__ db, short* __restrict__ dbz) {
    const int r    = blockIdx.x * 4 + (threadIdx.x >> 6);
    const int lane = threadIdx.x & 63;
    bf16x8 u = {0,0,0,0,0,0,0,0};
    if (r < DB_N) {
        const float* row = db + (size_t)r * DIM;
        const float4 a = *(const float4*)(row + lane * 8);
        const float4 b = *(const float4*)(row + lane * 8 + 4);
        float ss = a.x*a.x + a.y*a.y + a.z*a.z + a.w*a.w
                 + b.x*b.x + b.y*b.y + b.z*b.z + b.w*b.w;
        #pragma unroll
        for (int off = 1; off < 64; off <<= 1) ss += __shfl_xor(ss, off);
        const float inv = 1.0f / fmaxf(sqrtf(ss), 1e-12f);
        float4 an = {a.x*inv, a.y*inv, a.z*inv, a.w*inv};
        float4 bn = {b.x*inv, b.y*inv, b.z*inv, b.w*inv};
        u = pack8(an, bn);
    }
    const int kb = lane >> 3;         // this lane's 64-elem k-chunk
    const int w  = lane & 7;          // data unit within chunk
    *(bf16x8*)(dbz + ((size_t)kb * PADN + r) * 64 + ((w ^ (r & 7)) << 3)) = u;
}

// ============ kernel 1 (fast): fused sim GEMM + running top-5 ============
__global__ __launch_bounds__(512, 4) void sim_topk_kernel(
    const float* __restrict__ h, const short* __restrict__ dbz,
    float* __restrict__ pv, int* __restrict__ pi) {

    __shared__ __align__(16) short tile[2][BN * 64];   // 2 x 8KB, linear, swizzled content

    const int tid  = threadIdx.x;
    const int lane = tid & 63;
    const int wid  = tid >> 6;
    const int l15  = lane & 15;
    const int lhi  = lane >> 4;
    const int rb   = blockIdx.x >> 5;     // 0..15
    const int mc   = blockIdx.x & 31;     // 0..31
    const int m_base = mc * CHUNK;
    const int row_g  = rb * BM + wid * 16 + l15;

    // ---- A (raw h rows) -> registers as bf16; row norm on the fly
    const float* hrow = h + (size_t)row_g * DIM;
    float ss = 0.f;
    bf16x8 ha[16];
    #pragma unroll
    for (int t = 0; t < 16; ++t) {
        const float4 x = *(const float4*)(hrow + t * 32 + lhi * 8);
        const float4 y = *(const float4*)(hrow + t * 32 + lhi * 8 + 4);
        ss += x.x*x.x + x.y*x.y + x.z*x.z + x.w*x.w;
        ss += y.x*y.x + y.y*y.y + y.z*y.z + y.w*y.w;
        ha[t] = pack8(x, y);
    }
    ss += __shfl_xor(ss, 16);
    ss += __shfl_xor(ss, 32);
    const float inv_h = 1.0f / fmaxf(sqrtf(ss), 1e-12f);
    float ivc[4];
    #pragma unroll
    for (int i = 0; i < 4; ++i) ivc[i] = __shfl(inv_h, lhi * 4 + i, 64);

    float tv[4][TOPK]; int tix[4][TOPK];
    #pragma unroll
    for (int i = 0; i < 4; ++i)
        #pragma unroll
        for (int j = 0; j < TOPK; ++j) { tv[i][j] = -3.0e38f; tix[i][j] = 0; }

    // prologue: stage (tt=0, kb=0)
    async16(dbz + (size_t)m_base * 64 + tid * 8, (short*)tile[0] + tid * 8);
    __syncthreads();

    for (int tt = 0; tt < NTILES; ++tt) {
        const int m0 = m_base + tt * 64;

        f32x4 acc[4];
        #pragma unroll
        for (int f = 0; f < 4; ++f) acc[f] = (f32x4){0.f, 0.f, 0.f, 0.f};

        #pragma unroll
        for (int kb = 0; kb < 8; ++kb) {
            // stage next chunk (async, stays in flight under the MFMAs)
            if (!((tt == NTILES - 1) && (kb == 7))) {
                const int nkb = (kb + 1) & 7;
                const int nm0 = (kb == 7) ? (m0 + 64) : m0;
                async16(dbz + ((size_t)nkb * PADN + nm0) * 64 + tid * 8,
                        (short*)tile[(kb + 1) & 1] + tid * 8);
            }
            const char* tb = (const char*)tile[kb & 1];
            #pragma unroll
            for (int ks = 0; ks < 2; ++ks) {
                const bf16x8 a = ha[kb * 2 + ks];
                #pragma unroll
                for (int f = 0; f < 4; ++f) {
                    const int row = f * 16 + l15;
                    const int off = (row << 7) + ((ks * 64 + (lhi << 4)) ^ ((l15 & 7) << 4));
                    const bf16x8 bfr = *(const bf16x8*)(tb + off);
                    acc[f] = __builtin_amdgcn_mfma_f32_16x16x32_bf16(a, bfr, acc[f], 0, 0, 0);
                }
            }
            __syncthreads();
        }

        // ---- scale to cosine sims (db pre-normalized); mask pad columns
        const int mrows = DB_N - m0;     // may be <= 0 (all-pad tile)
        #pragma unroll
        for (int f = 0; f < 4; ++f) {
            const bool valid = (f * 16 + l15) < mrows;
            #pragma unroll
            for (int i = 0; i < 4; ++i)
                acc[f][i] = valid ? acc[f][i] * ivc[i] : -3.0e38f;
        }

        // ---- cheap pre-check: does any row have a candidate beating its 5th-best?
        int nb = 0;
        #pragma unroll
        for (int i = 0; i < 4; ++i) {
            float m = fmaxf(fmaxf(acc[0][i], acc[1][i]), fmaxf(acc[2][i], acc[3][i]));
            #pragma unroll
            for (int s = 1; s < 16; s <<= 1) m = fmaxf(m, __shfl_xor(m, s));
            nb |= (m > tv[i][TOPK - 1]) ? 1 : 0;
        }
        if (__any(nb)) {
            #pragma unroll 1
            for (int it = 0; it < TOPK; ++it) {
                float wv[4]; int wc[4];
                #pragma unroll
                for (int i = 0; i < 4; ++i) {
                    float v = acc[0][i]; int c = l15;
                    #pragma unroll
                    for (int f = 1; f < 4; ++f) {
                        const float v2 = acc[f][i]; const int c2 = f * 16 + l15;
                        if (v2 > v) { v = v2; c = c2; }
                    }
                    #pragma unroll
                    for (int s = 1; s < 16; s <<= 1) {
                        const float ov = __shfl_xor(v, s);
                        const int   oc = __shfl_xor(c, s);
                        if (ov > v || (ov == v && oc < c)) { v = ov; c = oc; }
                    }
                    wv[i] = v; wc[i] = c;
                }
                int more = 0;
                #pragma unroll
                for (int i = 0; i < 4; ++i) more |= (wv[i] > tv[i][TOPK - 1]) ? 1 : 0;
                if (!__any(more)) break;
                #pragma unroll
                for (int i = 0; i < 4; ++i) {
                    const float w  = wv[i];
                    const int   gi = m0 + wc[i];
                    #pragma unroll
                    for (int j = TOPK - 1; j >= 1; --j) {
                        const bool gt  = w > tv[i][j];
                        const bool gtp = w > tv[i][j - 1];
                        tv[i][j]  = gt ? (gtp ? tv[i][j - 1]  : w)  : tv[i][j];
                        tix[i][j] = gt ? (gtp ? tix[i][j - 1] : gi) : tix[i][j];
                    }
                    if (w > tv[i][0]) { tv[i][0] = w; tix[i][0] = gi; }
                    #pragma unroll
                    for (int f = 0; f < 4; ++f)
                        if (f * 16 + l15 == wc[i]) acc[f][i] = -3.0e38f;
                }
            }
        }
    }

    if (l15 == 0) {
        #pragma unroll
        for (int i = 0; i < 4; ++i) {
            const int    row  = rb * BM + wid * 16 + lhi * 4 + i;
            const size_t base = ((size_t)row * MSPLIT + mc) * TOPK;
            #pragma unroll
            for (int j = 0; j < TOPK; ++j) { pv[base + j] = tv[i][j]; pi[base + j] = tix[i][j]; }
        }
    }
}

// ============ kernel 2: merge chunks (wave-parallel), softmax, gather, blend ============
__global__ void finalize_kernel(const float* __restrict__ h, const float* __restrict__ db,
                                const float* __restrict__ alpha_p,
                                const float* __restrict__ pv, const int* __restrict__ pi,
                                float* __restrict__ out, int ncand) {
    const int b   = blockIdx.x;
    const int tid = threadIdx.x;
    __shared__ float mu_s[TOPK];
    __shared__ int   id_s[TOPK];
    if (tid < 64) {
        const float* vp = pv + (size_t)b * ncand;
        const int*   ip = pi + (size_t)b * ncand;
        float v[3]; int ix[3];
        #pragma unroll
        for (int j = 0; j < 3; ++j) {
            const int c  = tid + j * 64;
            const bool ok = c < ncand;
            v[j]  = ok ? vp[c] : -3.0e38f;
            ix[j] = ok ? ip[c] : 0x7fffffff;
        }
        float bv[TOPK]; int bi[TOPK];
        #pragma unroll
        for (int it = 0; it < TOPK; ++it) {
            float m = v[0]; int mi = ix[0];
            if (v[1] > m || (v[1] == m && ix[1] < mi)) { m = v[1]; mi = ix[1]; }
            if (v[2] > m || (v[2] == m && ix[2] < mi)) { m = v[2]; mi = ix[2]; }
            #pragma unroll
            for (int s = 1; s < 64; s <<= 1) {
                const float om = __shfl_xor(m, s);
                const int   oi = __shfl_xor(mi, s);
                if (om > m || (om == m && oi < mi)) { m = om; mi = oi; }
            }
            bv[it] = m; bi[it] = mi;
            #pragma unroll
            for (int j = 0; j < 3; ++j) if (ix[j] == mi) v[j] = -3.0e38f;
        }
        if (tid == 0) {
            float s = 0.f, w[TOPK];
            #pragma unroll
            for (int j = 0; j < TOPK; ++j) { w[j] = expf(bv[j] - bv[0]); s += w[j]; }
            #pragma unroll
            for (int j = 0; j < TOPK; ++j) { mu_s[j] = w[j] / s; id_s[j] = bi[j]; }
        }
    }
    __syncthreads();
    const float a = 1.0f / (1.0f + expf(-alpha_p[0]));
    for (int d = tid; d < DIM; d += 256) {
        float r = 0.f;
        #pragma unroll
        for (int j = 0; j < TOPK; ++j) r += mu_s[j] * db[(size_t)id_s[j] * DIM + d];
        out[(size_t)b * DIM + d] = a * h[(size_t)b * DIM + d] + (1.f - a) * r;
    }
}

// ======================= fallback path (round-1, small ws) =======================
__global__ void inv_norm_kernel(const float* __restrict__ db, float* __restrict__ inv_db) {
    const int g    = blockIdx.x * (blockDim.x >> 6) + (threadIdx.x >> 6);
    const int lane = threadIdx.x & 63;
    if (g >= DB_N) return;
    const float* row = db + (size_t)g * DIM;
    const float4 a = *(const float4*)(row + lane * 8);
    const float4 b = *(const float4*)(row + lane * 8 + 4);
    float s = a.x*a.x + a.y*a.y + a.z*a.z + a.w*a.w
            + b.x*b.x + b.y*b.y + b.z*b.z + b.w*b.w;
    #pragma unroll
    for (int off = 32; off >= 1; off >>= 1) s += __shfl_xor(s, off);
    if (lane == 0) inv_db[g] = 1.0f / fmaxf(sqrtf(s), 1e-12f);
}

__global__ __launch_bounds__(512, 1) void sim_topk_fb(
    const float* __restrict__ h, const float* __restrict__ db,
    const float* __restrict__ inv_db,
    float* __restrict__ pv, int* __restrict__ pi) {

    __shared__ __align__(16) short tile[2][BN][LDSPAD];
    const int tid  = threadIdx.x;
    const int lane = tid & 63;
    const int wid  = tid >> 6;
    const int l15  = lane & 15;
    const int lhi  = lane >> 4;
    const int rb   = blockIdx.x >> 4;
    const int mc   = blockIdx.x & 15;
    const int m_base = mc * FCHUNK;
    const int row_g  = rb * BM + wid * 16 + l15;

    const float* hrow = h + (size_t)row_g * DIM;
    float ss = 0.f;
    bf16x8 ha[16];
    #pragma unroll
    for (int t = 0; t < 16; ++t) {
        const float4 x = *(const float4*)(hrow + t * 32 + lhi * 8);
        const float4 y = *(const float4*)(hrow + t * 32 + lhi * 8 + 4);
        ss += x.x*x.x + x.y*x.y + x.z*x.z + x.w*x.w;
        ss += y.x*y.x + y.y*y.y + y.z*y.z + y.w*y.w;
        ha[t] = pack8(x, y);
    }
    ss += __shfl_xor(ss, 16);
    ss += __shfl_xor(ss, 32);
    const float inv_h = 1.0f / fmaxf(sqrtf(ss), 1e-12f);
    float ivc[4];
    #pragma unroll
    for (int i = 0; i < 4; ++i) ivc[i] = __shfl(inv_h, lhi * 4 + i, 64);

    float tv[4][TOPK]; int tix[4][TOPK];
    #pragma unroll
    for (int i = 0; i < 4; ++i)
        #pragma unroll
        for (int j = 0; j < TOPK; ++j) { tv[i][j] = -3.0e38f; tix[i][j] = 0; }

    const int srow = tid >> 3;
    const int skc  = (tid & 7) * 8;

    for (int tt = 0; tt < FNTILES; ++tt) {
        const int m0    = m_base + tt * BN;
        const int mrows = (m_base + FCHUNK - m0 < BN) ? (m_base + FCHUNK - m0) : BN;

        f32x4 acc[4];
        #pragma unroll
        for (int f = 0; f < 4; ++f) acc[f] = (f32x4){0.f, 0.f, 0.f, 0.f};

        {
            float4 x = {0,0,0,0}, y = {0,0,0,0};
            if (srow < mrows) {
                const float* p = db + (size_t)(m0 + srow) * DIM + skc;
                x = *(const float4*)p; y = *(const float4*)(p + 4);
            }
            *(bf16x8*)(&tile[0][srow][skc]) = pack8(x, y);
        }
        __syncthreads();

        #pragma unroll
        for (int kb = 0; kb < 8; ++kb) {
            float4 px = {0,0,0,0}, py = {0,0,0,0};
            if (kb < 7) {
                if (srow < mrows) {
                    const float* p = db + (size_t)(m0 + srow) * DIM + (kb + 1) * 64 + skc;
                    px = *(const float4*)p; py = *(const float4*)(p + 4);
                }
            }
            const short* tb = &tile[kb & 1][0][0];
            #pragma unroll
            for (int ks = 0; ks < 2; ++ks) {
                const bf16x8 a = ha[kb * 2 + ks];
                #pragma unroll
                for (int f = 0; f < 4; ++f) {
                    const bf16x8 bfr = *(const bf16x8*)(tb + (f * 16 + l15) * LDSPAD + ks * 32 + lhi * 8);
                    acc[f] = __builtin_amdgcn_mfma_f32_16x16x32_bf16(a, bfr, acc[f], 0, 0, 0);
                }
            }
            if (kb < 7) {
                *(bf16x8*)(&tile[(kb + 1) & 1][srow][skc]) = pack8(px, py);
                __syncthreads();
            }
        }

        #pragma unroll
        for (int f = 0; f < 4; ++f) {
            const int  c     = f * 16 + l15;
            const bool valid = c < mrows;
            const float idb  = valid ? inv_db[m0 + c] : 0.f;
            #pragma unroll
            for (int i = 0; i < 4; ++i)
                acc[f][i] = valid ? acc[f][i] * ivc[i] * idb : -3.0e38f;
        }

        #pragma unroll 1
        for (int it = 0; it < TOPK; ++it) {
            float wv[4]; int wc[4];
            #pragma unroll
            for (int i = 0; i < 4; ++i) {
                float v = acc[0][i]; int c = l15;
                #pragma unroll
                for (int f = 1; f < 4; ++f) {
                    const float v2 = acc[f][i]; const int c2 = f * 16 + l15;
                    if (v2 > v) { v = v2; c = c2; }
                }
                #pragma unroll
                for (int s = 1; s < 16; s <<= 1) {
                    const float ov = __shfl_xor(v, s);
                    const int   oc = __shfl_xor(c, s);
                    if (ov > v || (ov == v && oc < c)) { v = ov; c = oc; }
                }
                wv[i] = v; wc[i] = c;
            }
            int nb = 0;
            #pragma unroll
            for (int i = 0; i < 4; ++i) nb |= (wv[i] > tv[i][TOPK - 1]) ? 1 : 0;
            if (!__any(nb)) break;
            #pragma unroll
            for (int i = 0; i < 4; ++i) {
                const float w  = wv[i];
                const int   gi = m0 + wc[i];
                #pragma unroll
                for (int j = TOPK - 1; j >= 1; --j) {
                    const bool gt  = w > tv[i][j];
                    const bool gtp = w > tv[i][j - 1];
                    tv[i][j]  = gt ? (gtp ? tv[i][j - 1]  : w)  : tv[i][j];
                    tix[i][j] = gt ? (gtp ? tix[i][j - 1] : gi) : tix[i][j];
                }
                if (w > tv[i][0]) { tv[i][0] = w; tix[i][0] = gi; }
                #pragma unroll
                for (int f = 0; f < 4; ++f)
                    if (f * 16 + l15 == wc[i]) acc[f][i] = -3.0e38f;
            }
        }
    }

    if (l15 == 0) {
        #pragma unroll
        for (int i = 0; i < 4; ++i) {
            const int    row  = rb * BM + wid * 16 + lhi * 4 + i;
            const size_t base = ((size_t)row * FMSPLIT + mc) * TOPK;
            #pragma unroll
            for (int j = 0; j < TOPK; ++j) { pv[base + j] = tv[i][j]; pi[base + j] = tix[i][j]; }
        }
    }
}

extern "C" void kernel_launch(void* const* d_in, const int* in_sizes, int n_in,
                              void* d_out, int out_size, void* d_ws, size_t ws_size,
                              hipStream_t stream) {
    const float* h     = (const float*)d_in[0];
    const float* db    = (const float*)d_in[1];
    const float* alpha = (const float*)d_in[2];
    float* out = (float*)d_out;

    const size_t dbz_bytes = (size_t)PADN * DIM * 2;              // 52,428,800
    const size_t pv_bytes  = (size_t)BATCH * MSPLIT * TOPK * 4;   // 1,310,720
    const size_t need      = dbz_bytes + 2 * pv_bytes;

    if (ws_size >= need) {
        short* dbz = (short*)d_ws;
        float* pv  = (float*)((char*)d_ws + dbz_bytes);
        int*   pi  = (int*)  ((char*)d_ws + dbz_bytes + pv_bytes);
        convert_db_kernel<<<PADN / 4, 256, 0, stream>>>(db, dbz);
        sim_topk_kernel<<<16 * MSPLIT, 512, 0, stream>>>(h, dbz, pv, pi);
        finalize_kernel<<<BATCH, 256, 0, stream>>>(h, db, alpha, pv, pi, out, MSPLIT * TOPK);
    } else {
        float* inv_db = (float*)d_ws;
        float* pv     = (float*)((char*)d_ws + 200704);
        int*   pi     = (int*)  ((char*)d_ws + 200704 + 655360);
        inv_norm_kernel<<<(DB_N + 3) / 4, 256, 0, stream>>>(db, inv_db);
        sim_topk_fb<<<16 * FMSPLIT, 512, 0, stream>>>(h, db, inv_db, pv, pi);
        finalize_kernel<<<BATCH, 256, 0, stream>>>(h, db, alpha, pv, pi, out, FMSPLIT * TOPK);
    }
}